// Round 6
// baseline (114.160 us; speedup 1.0000x reference)
//
#include <hip/hip_runtime.h>

// SIAF forward. Round 13: unshackle the register allocator.
// Round-12 finding: VGPR_Count == 32 in EVERY profiled variant (r9-r12),
// regardless of source-level double-buffering -- launch_bounds(512,8) caps
// VGPR at 64 and the allocator min-pressures to 32, sinking every load to its
// use. Result: each of the 16 windows serially exposes full L1/LDS/trans
// latency; issue-count cuts and occupancy were both null because the bound is
// exposed latency per wave, not issue or wave count.
// This round: launch_bounds(512,4) (VGPR cap 128, 2 blocks/CU -- occupancy
// proven irrelevant in r11), depth-2 A-frag prefetch (load w+2 issued right
// after window w's MFMAs free the buffer => one full window of compute covers
// the load latency). Cooperative launch DROPPED (r12: grid.sync spin, 300 us
// under rocprof, zero real gain). Two-kernel structure restored.
// Carried from r12 (verified absmax 0.0625): tanh affine fold into W2'/b2'
// (tanh = 1-2r, r=1/(exp2(t)+1)), log2-domain alpha (exp2 epilogue, *LN2 after
// logdet reduce), pad-lane select hoisted to w==15, linear global W1 image,
// 512-thr blocks, 39.4 KB LDS.
// Checkable prediction: VGPR_Count 32 -> >=80. If total unchanged while VGPR
// rose, latency theory is wrong -> next: Pade-tanh / 2-samples-per-lane.

#define DIMS 64
#define TPB  512
#define WAVES 8
#define SPW  16

typedef __attribute__((ext_vector_type(8))) short short8;
typedef __attribute__((ext_vector_type(4))) float f32x4;
typedef __attribute__((ext_vector_type(4))) unsigned int uint4v;
typedef unsigned short ushort_t;
typedef unsigned int uint_t;

#if __has_builtin(__builtin_amdgcn_exp2f)
#define YSCALE 2.8853900817779268f      /* 2*log2(e): exp(2y) = exp2(YSCALE*y) */
#define EXP2F(x) __builtin_amdgcn_exp2f(x)
#else
#define YSCALE 2.8853900817779268f
#define EXP2F(x) exp2f(x)
#endif
#define LOG2E 1.4426950408889634f
#define LN2   0.6931471805599453f

// g_ws global image layout (bytes) -- LINEAR, coalesced global reads:
//  A   [0,16384):      w1 rows p<256 (w<8), 64 B/row, k=0..31
//  Blo [16384,32768):  w1 rows p in [256,512), 64 B/row, k=0..31
//  Bhi [32768,49152):  w1 rows p in [256,512), 64 B/row, k=32..63
//  C'  [49152,53248):  -2*W2 fp32 [64 l][2 o][8 h], o=1 row additionally *LOG2E
//  D   [53248,55296):  b1 fp32 [512] physical row order, *YSCALE
//  E'  [55296,55808):  (b2+rowsum W2) fp32 [64][2], o=1 *LOG2E
#define A_OFF 0
#define BLO_OFF 16384
#define BHI_OFF 32768
#define C_OFF 49152
#define WT_BYTES 55808
#define CDE_BYTES 6656
#define PREP_N (24576 + 1664)

// LDS: [0,4096) W2' | [4096,6144) b1 | [6144,6656) b2' | [6656,+32768) xz
#define XZ_OFF CDE_BYTES
#define LDS_BYTES (CDE_BYTES + WAVES * SPW * DIMS * 4)   // 6656 + 32768 = 39424

__device__ __align__(16) unsigned char g_ws[WT_BYTES];

__device__ __forceinline__ uint_t pk2bf(float a, float b) {
#if __has_builtin(__builtin_amdgcn_cvt_pk_bf16_f32)
    typedef __attribute__((ext_vector_type(2))) __bf16 bf16x2;
    bf16x2 r = __builtin_amdgcn_cvt_pk_bf16_f32(a, b);
    return __builtin_bit_cast(uint_t, r);
#else
    uint_t ua = __float_as_uint(a); ua += 0x7FFFu + ((ua >> 16) & 1u);
    uint_t ub = __float_as_uint(b); ub += 0x7FFFu + ((ub >> 16) & 1u);
    return (ub & 0xFFFF0000u) | (ua >> 16);
#endif
}

__device__ __forceinline__ ushort_t f2bf(float f) {
    uint_t u = __float_as_uint(f);
    u += 0x7FFFu + ((u >> 16) & 1u);
    return (ushort_t)(u >> 16);
}

// logical row L for physical GEMM1 row p (window w=p>>5, tile parity e=(p>>4)&1,
// n=p&15): L = w*32 + (n>>2)*8 + e*4 + (n&3);  l = L>>3, h = L&7.
__device__ __forceinline__ int logrow(int p) {
    int n = p & 15;
    return (p >> 5) * 32 + (n >> 2) * 8 + ((p >> 4) & 1) * 4 + (n & 3);
}

__global__ void siaf_prep(const float* __restrict__ W1, const float* __restrict__ b1,
                          const float* __restrict__ W2, const float* __restrict__ b2) {
    ushort_t* __restrict__ ws_u = (ushort_t*)g_ws;
    int i = blockIdx.x * 256 + threadIdx.x;
    if (i < 8192) {                       // region A: p<256, linear k
        int p = i >> 5, k = i & 31;
        int L = logrow(p), l = L >> 3, h = L & 7;
        float v = (k <= l) ? W1[(l * 8 + h) * 63 + k] * YSCALE : 0.0f;
        ws_u[i] = f2bf(v);
    } else if (i < 16384) {               // region B-lo: p in [256,512), k<32
        int r = i - 8192;
        int p = 256 + (r >> 5), k = r & 31;
        int L = logrow(p), l = L >> 3, h = L & 7;
        float v = (l < 63 && k <= l) ? W1[(l * 8 + h) * 63 + k] * YSCALE : 0.0f;
        ws_u[i] = f2bf(v);
    } else if (i < 24576) {               // region B-hi: p in [256,512), k>=32
        int r = i - 16384;
        int p = 256 + (r >> 5), k = 32 + (r & 31);
        int L = logrow(p), l = L >> 3, h = L & 7;
        float v = (l < 63 && k <= l) ? W1[(l * 8 + h) * 63 + k] * YSCALE : 0.0f;
        ws_u[i] = f2bf(v);
    } else if (i < PREP_N) {              // fp32 regions C'/D/E'
        int f = i - 24576;
        float* fws = (float*)(g_ws + C_OFF);
        float v = 0.0f;
        if (f < 1024) {                   // C': -2*W2 (alpha row *LOG2E)
            int l = f >> 4, o = (f >> 3) & 1, h = f & 7;
            if (l < 63) {
                v = -2.0f * W2[(l * 2 + o) * 8 + h];
                if (o) v *= LOG2E;
            }
        } else if (f < 1536) {            // D: b1 in physical row order
            int p = f - 1024;
            int L = logrow(p), l = L >> 3, h = L & 7;
            if (l < 63) v = b1[l * 8 + h] * YSCALE;
        } else {                          // E': b2 + rowsum(W2) (alpha *LOG2E)
            int j = f - 1536, l = j >> 1, o = j & 1;
            if (l < 63) {
                float s = b2[l * 2 + o];
                #pragma unroll
                for (int h = 0; h < 8; ++h) s += W2[(l * 2 + o) * 8 + h];
                v = o ? s * LOG2E : s;
            }
        }
        fws[f] = v;
    }
}

// r = 1/(exp2(t)+1); tanh(y) = 1 - 2r is folded into W2'/b2'.
__device__ __forceinline__ float sg(float t) {
    float e = EXP2F(t);
    return __builtin_amdgcn_rcpf(e + 1.0f);
}

__global__ __launch_bounds__(TPB, 4) void siaf_main(
        const float* __restrict__ x, const float* __restrict__ ip,
        float* __restrict__ out, int nB) {
    extern __shared__ unsigned char lds[];

    const int tid  = threadIdx.x;
    const int wv   = tid >> 6, lane = tid & 63;
    const int s16  = lane & 15, quad = lane >> 4;
    const int sbase = blockIdx.x * (WAVES * SPW) + wv * SPW;
    float* xzw = (float*)(lds + XZ_OFF) + wv * (SPW * DIMS);

    // ---- stage x (own-wave LDS region): coalesced 1KB/instr, 16B-chunk XOR
    // swizzle (key = row). Global latency overlaps CDE stage below.
    #pragma unroll
    for (int g = 0; g < 4; ++g) {
        const float4 v = ((const float4*)(x + (size_t)sbase * DIMS))[g * 64 + lane];
        const int s_loc = 4 * g + quad;
        const int pc = (s16 ^ s_loc) & 15;
        *(float4*)(xzw + s_loc * 64 + pc * 4) = v;
    }
    const float ip0 = ip[0];
    const float ip1l2 = ip[1] * LOG2E;

    // ---- stage C'/D/E' (6656 B) into LDS ----
    if (tid < CDE_BYTES / 16) {
        ((uint4*)lds)[tid] = ((const uint4*)(g_ws + C_OFF))[tid];
    }

    // ---- B-frag: B[k=quad*8+j][n=s16] from own-wave LDS region, bf16 ----
    short8 bfr[2];
    #pragma unroll
    for (int kh = 0; kh < 2; ++kh) {
        const int c0 = kh * 8 + quad * 2;
        float4 va = *(const float4*)(xzw + s16 * 64 + ((c0 ^ s16) & 15) * 4);
        float4 vb = *(const float4*)(xzw + s16 * 64 + (((c0 + 1) ^ s16) & 15) * 4);
        uint4v u = {pk2bf(va.x, va.y), pk2bf(va.z, va.w),
                    pk2bf(vb.x, vb.y), pk2bf(vb.z, vb.w)};
        bfr[kh] = __builtin_bit_cast(short8, u);
    }

    __syncthreads();   // C'/D/E' image ready for all waves

    const float* w2f = (const float*)(lds);
    const float* b1f = (const float*)(lds + 4096);
    const float* b2f = (const float*)(lds + 6144);

    const ushort_t* gA   = (const ushort_t*)g_ws;
    const ushort_t* gBlo = (const ushort_t*)(g_ws + BLO_OFF);
    const ushort_t* gBhi = (const ushort_t*)(g_ws + BHI_OFF);
    const int fo = s16 * 32 + quad * 8;

    auto ldA = [&](int w, short8& a00, short8& a10, short8& a01, short8& a11) {
        if (w < 8) {
            const ushort_t* b = gA + w * 1024 + fo;
            a00 = *(const short8*)(b);
            a10 = *(const short8*)(b + 512);
        } else {
            const int off = (w - 8) * 1024 + fo;
            a00 = *(const short8*)(gBlo + off);
            a10 = *(const short8*)(gBlo + off + 512);
            a01 = *(const short8*)(gBhi + off);
            a11 = *(const short8*)(gBhi + off + 512);
        }
    };

    // depth-2 prefetch ring: buffer (w&1) holds window w's frags.
    short8 A00[2], A10[2], A01[2] = {}, A11[2] = {};
    ldA(0, A00[0], A10[0], A01[0], A11[0]);
    ldA(1, A00[1], A10[1], A01[1], A11[1]);

    float lsum = 0.0f;
    #pragma unroll
    for (int w = 0; w < 16; ++w) {
        const int cur = w & 1;

        // bias init + MFMAs consume buffer cur
        const float4 bi0 = *(const float4*)(b1f + w * 32 + quad * 4);
        const float4 bi1 = *(const float4*)(b1f + w * 32 + 16 + quad * 4);

        f32x4 aE = {bi0.x, bi0.y, bi0.z, bi0.w};
        f32x4 aO = {bi1.x, bi1.y, bi1.z, bi1.w};
        aE = __builtin_amdgcn_mfma_f32_16x16x32_bf16(A00[cur], bfr[0], aE, 0, 0, 0);
        aO = __builtin_amdgcn_mfma_f32_16x16x32_bf16(A10[cur], bfr[0], aO, 0, 0, 0);
        if (w >= 8) {
            aE = __builtin_amdgcn_mfma_f32_16x16x32_bf16(A01[cur], bfr[1], aE, 0, 0, 0);
            aO = __builtin_amdgcn_mfma_f32_16x16x32_bf16(A11[cur], bfr[1], aO, 0, 0, 0);
        }

        // buffer cur is now free: issue window w+2's loads immediately so the
        // remaining ~full window of compute (sg/GEMM2/epilogue) hides latency.
        if (w < 14) ldA(w + 2, A00[cur], A10[cur], A01[cur], A11[cur]);

        // lane owns layer l = 4w+quad, sample s16
        const float r0 = sg(aE[0]), r1 = sg(aE[1]), r2 = sg(aE[2]), r3 = sg(aE[3]);
        const float r4 = sg(aO[0]), r5 = sg(aO[1]), r6 = sg(aO[2]), r7 = sg(aO[3]);

        const int l = 4 * w + quad;
        const float4 m0 = *(const float4*)(w2f + l * 16);
        const float4 m1 = *(const float4*)(w2f + l * 16 + 4);
        const float4 a0 = *(const float4*)(w2f + l * 16 + 8);
        const float4 a1 = *(const float4*)(w2f + l * 16 + 12);
        const float2 bb = *(const float2*)(b2f + l * 2);

        // GEMM2 (tanh affine part pre-folded): two 4-deep partials per output
        float mu0 = bb.x, mu1 = m1.x * r4;
        mu0 = fmaf(m0.x, r0, mu0); mu1 = fmaf(m1.y, r5, mu1);
        mu0 = fmaf(m0.y, r1, mu0); mu1 = fmaf(m1.z, r6, mu1);
        mu0 = fmaf(m0.z, r2, mu0); mu1 = fmaf(m1.w, r7, mu1);
        mu0 = fmaf(m0.w, r3, mu0);
        float mu = mu0 + mu1;
        float al0 = bb.y, al1 = a1.x * r4;
        al0 = fmaf(a0.x, r0, al0); al1 = fmaf(a1.y, r5, al1);
        al0 = fmaf(a0.y, r1, al0); al1 = fmaf(a1.z, r6, al1);
        al0 = fmaf(a0.z, r2, al0); al1 = fmaf(a1.w, r7, al1);
        al0 = fmaf(a0.w, r3, al0);
        float alg = al0 + al1;          // alpha in log2 domain

        int d = l + 1;
        if (w == 15) {                   // compile-time: pad lane handling only here
            const bool pad = (quad == 3);       // l == 63
            alg = pad ? ip1l2 : alg;
            mu  = pad ? ip0 : mu;
            d   = pad ? 0 : d;
        }
        float* pz = xzw + s16 * 64 + ((((d >> 2) ^ s16) & 15) << 2) + (d & 3);
        *pz = fmaf(*pz, EXP2F(alg), mu);
        lsum += alg;
    }

    // ---- coalesced LDS -> global z store ----
    #pragma unroll
    for (int g = 0; g < 4; ++g) {
        const int s_loc = 4 * g + quad;
        const int pc = (s16 ^ s_loc) & 15;
        const float4 v = *(const float4*)(xzw + s_loc * 64 + pc * 4);
        ((float4*)(out + (size_t)sbase * DIMS))[g * 64 + lane] = v;
    }

    // ---- log_det: sum 4 quad-partials per sample, rescale log2 -> ln ----
    {
        float v = lsum;
        int r1 = __builtin_amdgcn_ds_swizzle(__float_as_int(v), 0x401F);  // xor 16
        v += __int_as_float(r1);
        int r2 = __builtin_amdgcn_ds_bpermute((lane ^ 32) << 2, __float_as_int(v));
        v += __int_as_float(r2);
        if (quad == 0)
            out[(size_t)nB * DIMS + sbase + s16] = v * LN2;
    }
}

extern "C" void kernel_launch(void* const* d_in, const int* in_sizes, int n_in,
                              void* d_out, int out_size, void* d_ws, size_t ws_size,
                              hipStream_t stream) {
    const float* x  = (const float*)d_in[0];
    const float* ip = (const float*)d_in[1];
    const float* W1 = (const float*)d_in[2];
    const float* b1 = (const float*)d_in[3];
    const float* W2 = (const float*)d_in[4];
    const float* b2 = (const float*)d_in[5];
    float* out = (float*)d_out;
    (void)d_ws; (void)ws_size;              // workspace unused (poison is unconditional)

    const int nB = in_sizes[0] / DIMS;      // 131072
    const int grid = nB / (WAVES * SPW);    // 1024

    (void)hipFuncSetAttribute((const void*)siaf_main,
                              hipFuncAttributeMaxDynamicSharedMemorySize, LDS_BYTES);

    siaf_prep<<<(PREP_N + 255) / 256, 256, 0, stream>>>(W1, b1, W2, b2);
    siaf_main<<<grid, TPB, LDS_BYTES, stream>>>(x, ip, out, nB);
}

// Round 7
// 110.404 us; speedup vs baseline: 1.0340x; 1.0340x over previous
//
#include <hip/hip_runtime.h>

// SIAF forward. Round 14: structural in-wave ILP=2 (two sample groups/wave).
// r9-r13: main pinned at ~41us across occupancy (1-4 blk/CU), LDS-vs-global
// weights, prefetch depth, VGPR cap, -15% instructions. Issue-work model says
// ~20us even with ZERO inter-pipe overlap -> the 2x gap is exposed per-wave
// dependency latency (bias-LDS -> MFMA -> trans chain -> FMA chain -> LDS-RMW
// ~600cy x16 windows), with lockstep waves stalling together. Register-based
// prefetch couldn't fix it (allocator sinks loads; VGPR stayed 32 whenever
// observable). This round makes the ILP structural: SPW=32, each wave carries
// TWO B-frags (samples s16, s16+16) and runs two complete independent chains
// per window off the SAME A-frags and SAME GEMM2 weights. Benefits: ILP=2 at
// every stage (allocator can't remove it), 2x amortized A-frag L1 + GEMM2 LDS
// traffic, grid=512=2 blocks/CU exactly (one generation, no tail).
// LDS 72.2KB -> 2 blk/CU, 4 waves/SIMD; A-frags single-buffered (~110 VGPR).
// Carried from r12/r13 (verified absmax 0.0625): tanh affine fold into
// W2'/b2' (tanh=1-2r, r=1/(exp2(t)+1)), log2-domain alpha, pad-select only at
// w==15, linear global W1 image, two-kernel structure (prep -> g_ws).
// If null: per-wave and per-SIMD levers exhausted -> declare roofline.

#define DIMS 64
#define TPB  512
#define WAVES 8
#define SPW  32

typedef __attribute__((ext_vector_type(8))) short short8;
typedef __attribute__((ext_vector_type(4))) float f32x4;
typedef __attribute__((ext_vector_type(4))) unsigned int uint4v;
typedef unsigned short ushort_t;
typedef unsigned int uint_t;

#if __has_builtin(__builtin_amdgcn_exp2f)
#define YSCALE 2.8853900817779268f      /* 2*log2(e): exp(2y) = exp2(YSCALE*y) */
#define EXP2F(x) __builtin_amdgcn_exp2f(x)
#else
#define YSCALE 2.8853900817779268f
#define EXP2F(x) exp2f(x)
#endif
#define LOG2E 1.4426950408889634f
#define LN2   0.6931471805599453f

// g_ws global image layout (bytes) -- LINEAR, coalesced global reads:
//  A   [0,16384):      w1 rows p<256 (w<8), 64 B/row, k=0..31
//  Blo [16384,32768):  w1 rows p in [256,512), 64 B/row, k=0..31
//  Bhi [32768,49152):  w1 rows p in [256,512), 64 B/row, k=32..63
//  C'  [49152,53248):  -2*W2 fp32 [64 l][2 o][8 h], o=1 row additionally *LOG2E
//  D   [53248,55296):  b1 fp32 [512] physical row order, *YSCALE
//  E'  [55296,55808):  (b2+rowsum W2) fp32 [64][2], o=1 *LOG2E
#define A_OFF 0
#define BLO_OFF 16384
#define BHI_OFF 32768
#define C_OFF 49152
#define WT_BYTES 55808
#define CDE_BYTES 6656
#define PREP_N (24576 + 1664)

// LDS: [0,4096) W2' | [4096,6144) b1 | [6144,6656) b2' | [6656,+65536) xz
#define XZ_OFF CDE_BYTES
#define LDS_BYTES (CDE_BYTES + WAVES * SPW * DIMS * 4)   // 6656 + 65536 = 72192

__device__ __align__(16) unsigned char g_ws[WT_BYTES];

__device__ __forceinline__ uint_t pk2bf(float a, float b) {
#if __has_builtin(__builtin_amdgcn_cvt_pk_bf16_f32)
    typedef __attribute__((ext_vector_type(2))) __bf16 bf16x2;
    bf16x2 r = __builtin_amdgcn_cvt_pk_bf16_f32(a, b);
    return __builtin_bit_cast(uint_t, r);
#else
    uint_t ua = __float_as_uint(a); ua += 0x7FFFu + ((ua >> 16) & 1u);
    uint_t ub = __float_as_uint(b); ub += 0x7FFFu + ((ub >> 16) & 1u);
    return (ub & 0xFFFF0000u) | (ua >> 16);
#endif
}

__device__ __forceinline__ ushort_t f2bf(float f) {
    uint_t u = __float_as_uint(f);
    u += 0x7FFFu + ((u >> 16) & 1u);
    return (ushort_t)(u >> 16);
}

// logical row L for physical GEMM1 row p (window w=p>>5, tile parity e=(p>>4)&1,
// n=p&15): L = w*32 + (n>>2)*8 + e*4 + (n&3);  l = L>>3, h = L&7.
__device__ __forceinline__ int logrow(int p) {
    int n = p & 15;
    return (p >> 5) * 32 + (n >> 2) * 8 + ((p >> 4) & 1) * 4 + (n & 3);
}

__global__ void siaf_prep(const float* __restrict__ W1, const float* __restrict__ b1,
                          const float* __restrict__ W2, const float* __restrict__ b2) {
    ushort_t* __restrict__ ws_u = (ushort_t*)g_ws;
    int i = blockIdx.x * 256 + threadIdx.x;
    if (i < 8192) {                       // region A: p<256, linear k
        int p = i >> 5, k = i & 31;
        int L = logrow(p), l = L >> 3, h = L & 7;
        float v = (k <= l) ? W1[(l * 8 + h) * 63 + k] * YSCALE : 0.0f;
        ws_u[i] = f2bf(v);
    } else if (i < 16384) {               // region B-lo: p in [256,512), k<32
        int r = i - 8192;
        int p = 256 + (r >> 5), k = r & 31;
        int L = logrow(p), l = L >> 3, h = L & 7;
        float v = (l < 63 && k <= l) ? W1[(l * 8 + h) * 63 + k] * YSCALE : 0.0f;
        ws_u[i] = f2bf(v);
    } else if (i < 24576) {               // region B-hi: p in [256,512), k>=32
        int r = i - 16384;
        int p = 256 + (r >> 5), k = 32 + (r & 31);
        int L = logrow(p), l = L >> 3, h = L & 7;
        float v = (l < 63 && k <= l) ? W1[(l * 8 + h) * 63 + k] * YSCALE : 0.0f;
        ws_u[i] = f2bf(v);
    } else if (i < PREP_N) {              // fp32 regions C'/D/E'
        int f = i - 24576;
        float* fws = (float*)(g_ws + C_OFF);
        float v = 0.0f;
        if (f < 1024) {                   // C': -2*W2 (alpha row *LOG2E)
            int l = f >> 4, o = (f >> 3) & 1, h = f & 7;
            if (l < 63) {
                v = -2.0f * W2[(l * 2 + o) * 8 + h];
                if (o) v *= LOG2E;
            }
        } else if (f < 1536) {            // D: b1 in physical row order
            int p = f - 1024;
            int L = logrow(p), l = L >> 3, h = L & 7;
            if (l < 63) v = b1[l * 8 + h] * YSCALE;
        } else {                          // E': b2 + rowsum(W2) (alpha *LOG2E)
            int j = f - 1536, l = j >> 1, o = j & 1;
            if (l < 63) {
                float s = b2[l * 2 + o];
                #pragma unroll
                for (int h = 0; h < 8; ++h) s += W2[(l * 2 + o) * 8 + h];
                v = o ? s * LOG2E : s;
            }
        }
        fws[f] = v;
    }
}

// r = 1/(exp2(t)+1); tanh(y) = 1 - 2r is folded into W2'/b2'.
__device__ __forceinline__ float sg(float t) {
    float e = EXP2F(t);
    return __builtin_amdgcn_rcpf(e + 1.0f);
}

__global__ __launch_bounds__(TPB, 4) void siaf_main(
        const float* __restrict__ x, const float* __restrict__ ip,
        float* __restrict__ out, int nB) {
    extern __shared__ unsigned char lds[];

    const int tid  = threadIdx.x;
    const int wv   = tid >> 6, lane = tid & 63;
    const int s16  = lane & 15, quad = lane >> 4;
    const int sbase = blockIdx.x * (WAVES * SPW) + wv * SPW;
    float* xzw = (float*)(lds + XZ_OFF) + wv * (SPW * DIMS);

    // ---- stage x (own-wave LDS region, 32 samples): coalesced 1KB/instr,
    // 16B-chunk XOR swizzle (key = row). Overlaps CDE stage below.
    #pragma unroll
    for (int g = 0; g < 8; ++g) {
        const float4 v = ((const float4*)(x + (size_t)sbase * DIMS))[g * 64 + lane];
        const int s_loc = 4 * g + quad;                 // rows 0..31
        const int pc = (s16 ^ s_loc) & 15;
        *(float4*)(xzw + s_loc * 64 + pc * 4) = v;
    }
    const float ip0 = ip[0];
    const float ip1l2 = ip[1] * LOG2E;

    // ---- stage C'/D/E' (6656 B) into LDS ----
    if (tid < CDE_BYTES / 16) {
        ((uint4*)lds)[tid] = ((const uint4*)(g_ws + C_OFF))[tid];
    }

    // ---- B-frags for BOTH sample groups: B[k=quad*8+j][n=s16(+16)] ----
    short8 bfA[2], bfB[2];
    #pragma unroll
    for (int grp = 0; grp < 2; ++grp) {
        const int s = s16 + 16 * grp;
        #pragma unroll
        for (int kh = 0; kh < 2; ++kh) {
            const int c0 = kh * 8 + quad * 2;
            float4 va = *(const float4*)(xzw + s * 64 + ((c0 ^ s) & 15) * 4);
            float4 vb = *(const float4*)(xzw + s * 64 + (((c0 + 1) ^ s) & 15) * 4);
            uint4v u = {pk2bf(va.x, va.y), pk2bf(va.z, va.w),
                        pk2bf(vb.x, vb.y), pk2bf(vb.z, vb.w)};
            (grp ? bfB : bfA)[kh] = __builtin_bit_cast(short8, u);
        }
    }

    __syncthreads();   // C'/D/E' image ready for all waves

    const float* w2f = (const float*)(lds);
    const float* b1f = (const float*)(lds + 4096);
    const float* b2f = (const float*)(lds + 6144);

    const ushort_t* gA   = (const ushort_t*)g_ws;
    const ushort_t* gBlo = (const ushort_t*)(g_ws + BLO_OFF);
    const ushort_t* gBhi = (const ushort_t*)(g_ws + BHI_OFF);
    const int fo = s16 * 32 + quad * 8;

    float lsA = 0.0f, lsB = 0.0f;
    #pragma unroll
    for (int w = 0; w < 16; ++w) {
        // A-frags (shared by both groups), single-buffered direct load
        short8 a00, a10, a01{}, a11{};
        if (w < 8) {
            const ushort_t* b = gA + w * 1024 + fo;
            a00 = *(const short8*)(b);
            a10 = *(const short8*)(b + 512);
        } else {
            const int off = (w - 8) * 1024 + fo;
            a00 = *(const short8*)(gBlo + off);
            a10 = *(const short8*)(gBlo + off + 512);
            a01 = *(const short8*)(gBhi + off);
            a11 = *(const short8*)(gBhi + off + 512);
        }

        // bias (shared): accumulator init for both groups
        const float4 bi0 = *(const float4*)(b1f + w * 32 + quad * 4);
        const float4 bi1 = *(const float4*)(b1f + w * 32 + 16 + quad * 4);

        f32x4 aEa = {bi0.x, bi0.y, bi0.z, bi0.w};
        f32x4 aOa = {bi1.x, bi1.y, bi1.z, bi1.w};
        f32x4 aEb = aEa, aOb = aOa;
        aEa = __builtin_amdgcn_mfma_f32_16x16x32_bf16(a00, bfA[0], aEa, 0, 0, 0);
        aEb = __builtin_amdgcn_mfma_f32_16x16x32_bf16(a00, bfB[0], aEb, 0, 0, 0);
        aOa = __builtin_amdgcn_mfma_f32_16x16x32_bf16(a10, bfA[0], aOa, 0, 0, 0);
        aOb = __builtin_amdgcn_mfma_f32_16x16x32_bf16(a10, bfB[0], aOb, 0, 0, 0);
        if (w >= 8) {
            aEa = __builtin_amdgcn_mfma_f32_16x16x32_bf16(a01, bfA[1], aEa, 0, 0, 0);
            aEb = __builtin_amdgcn_mfma_f32_16x16x32_bf16(a01, bfB[1], aEb, 0, 0, 0);
            aOa = __builtin_amdgcn_mfma_f32_16x16x32_bf16(a11, bfA[1], aOa, 0, 0, 0);
            aOb = __builtin_amdgcn_mfma_f32_16x16x32_bf16(a11, bfB[1], aOb, 0, 0, 0);
        }

        // GEMM2 weights (shared by both groups): broadcast LDS reads
        const int l = 4 * w + quad;
        const float4 m0 = *(const float4*)(w2f + l * 16);
        const float4 m1 = *(const float4*)(w2f + l * 16 + 4);
        const float4 a0 = *(const float4*)(w2f + l * 16 + 8);
        const float4 a1 = *(const float4*)(w2f + l * 16 + 12);
        const float2 bb = *(const float2*)(b2f + l * 2);

        // two independent per-group tails (ILP=2 through trans/VALU/LDS)
        #pragma unroll
        for (int grp = 0; grp < 2; ++grp) {
            const f32x4 aE = grp ? aEb : aEa;
            const f32x4 aO = grp ? aOb : aOa;
            const int s = s16 + 16 * grp;

            const float r0 = sg(aE[0]), r1 = sg(aE[1]), r2 = sg(aE[2]), r3 = sg(aE[3]);
            const float r4 = sg(aO[0]), r5 = sg(aO[1]), r6 = sg(aO[2]), r7 = sg(aO[3]);

            float mu0 = bb.x, mu1 = m1.x * r4;
            mu0 = fmaf(m0.x, r0, mu0); mu1 = fmaf(m1.y, r5, mu1);
            mu0 = fmaf(m0.y, r1, mu0); mu1 = fmaf(m1.z, r6, mu1);
            mu0 = fmaf(m0.z, r2, mu0); mu1 = fmaf(m1.w, r7, mu1);
            mu0 = fmaf(m0.w, r3, mu0);
            float mu = mu0 + mu1;
            float al0 = bb.y, al1 = a1.x * r4;
            al0 = fmaf(a0.x, r0, al0); al1 = fmaf(a1.y, r5, al1);
            al0 = fmaf(a0.y, r1, al0); al1 = fmaf(a1.z, r6, al1);
            al0 = fmaf(a0.z, r2, al0); al1 = fmaf(a1.w, r7, al1);
            al0 = fmaf(a0.w, r3, al0);
            float alg = al0 + al1;          // alpha in log2 domain

            int d = l + 1;
            if (w == 15) {                   // compile-time: pad lane only here
                const bool pad = (quad == 3);       // l == 63
                alg = pad ? ip1l2 : alg;
                mu  = pad ? ip0 : mu;
                d   = pad ? 0 : d;
            }
            float* pz = xzw + s * 64 + ((((d >> 2) ^ s) & 15) << 2) + (d & 3);
            *pz = fmaf(*pz, EXP2F(alg), mu);
            if (grp) lsB += alg; else lsA += alg;
        }
    }

    // ---- coalesced LDS -> global z store (32 samples) ----
    #pragma unroll
    for (int g = 0; g < 8; ++g) {
        const int s_loc = 4 * g + quad;
        const int pc = (s16 ^ s_loc) & 15;
        const float4 v = *(const float4*)(xzw + s_loc * 64 + pc * 4);
        ((float4*)(out + (size_t)sbase * DIMS))[g * 64 + lane] = v;
    }

    // ---- log_det: sum 4 quad-partials per sample (both groups) ----
    {
        float va = lsA, vb = lsB;
        int r1a = __builtin_amdgcn_ds_swizzle(__float_as_int(va), 0x401F);  // xor 16
        int r1b = __builtin_amdgcn_ds_swizzle(__float_as_int(vb), 0x401F);
        va += __int_as_float(r1a);
        vb += __int_as_float(r1b);
        int r2a = __builtin_amdgcn_ds_bpermute((lane ^ 32) << 2, __float_as_int(va));
        int r2b = __builtin_amdgcn_ds_bpermute((lane ^ 32) << 2, __float_as_int(vb));
        va += __int_as_float(r2a);
        vb += __int_as_float(r2b);
        if (quad == 0) {
            out[(size_t)nB * DIMS + sbase + s16] = va * LN2;
            out[(size_t)nB * DIMS + sbase + 16 + s16] = vb * LN2;
        }
    }
}

extern "C" void kernel_launch(void* const* d_in, const int* in_sizes, int n_in,
                              void* d_out, int out_size, void* d_ws, size_t ws_size,
                              hipStream_t stream) {
    const float* x  = (const float*)d_in[0];
    const float* ip = (const float*)d_in[1];
    const float* W1 = (const float*)d_in[2];
    const float* b1 = (const float*)d_in[3];
    const float* W2 = (const float*)d_in[4];
    const float* b2 = (const float*)d_in[5];
    float* out = (float*)d_out;
    (void)d_ws; (void)ws_size;              // workspace unused (poison is unconditional)

    const int nB = in_sizes[0] / DIMS;      // 131072
    const int grid = nB / (WAVES * SPW);    // 512 = exactly 2 blocks/CU

    (void)hipFuncSetAttribute((const void*)siaf_main,
                              hipFuncAttributeMaxDynamicSharedMemorySize, LDS_BYTES);

    siaf_prep<<<(PREP_N + 255) / 256, 256, 0, stream>>>(W1, b1, W2, b2);
    siaf_main<<<grid, TPB, LDS_BYTES, stream>>>(x, ip, out, nB);
}